// Round 4
// baseline (160.671 us; speedup 1.0000x reference)
//
#include <hip/hip_runtime.h>

// Harness promotes float16 tensors to float32: x, scales, out are f32;
// weight_packed is int32, ONE BYTE (2 nibbles = 2 k-values) per element.
#define M 32
#define N 11008
#define K 4096
#define NGROUPS 32
#define BN 16                 // n-rows per block (one 16-wide MFMA n-tile)
#define KSPLIT 2              // grid-level k split
#define KRANGE (K / KSPLIT)   // 2048 k per block
#define KWAVE (KRANGE / 4)    // 512 k per wave = 4 scale groups
#define DEPTH 4               // per-wave pipeline depth (32-k steps in flight)
#define WSLOT 256             // ints per weight slot (1 KB = 16 rows x 32 k)
#define XSLOT 512             // ints per x slot (2 KB = 32 m-rows x 32 k f16)
#define LWAVE (DEPTH * (WSLOT + XSLOT)) // 3072 ints = 12 KB per wave
#define RS 17                 // epilogue reduce row stride (floats)

typedef _Float16 half8 __attribute__((ext_vector_type(8))); // 4 VGPRs
typedef _Float16 half4 __attribute__((ext_vector_type(4)));
typedef float floatx4 __attribute__((ext_vector_type(4)));

__device__ inline void gll16(const void* g, void* l) {
    __builtin_amdgcn_global_load_lds(
        (const __attribute__((address_space(1))) unsigned int*)g,
        (__attribute__((address_space(3))) unsigned int*)l, 16, 0, 0);
}

// 4 payload bytes (one per int) -> 8 f16 of (nibble - 8), exact 0x6400 trick
__device__ inline half8 unpack8(int4 wv) {
    uint4 uw; unsigned int b;
    b = (unsigned)wv.x; uw.x = ((b | (b << 12)) & 0x000F000Fu) | 0x64006400u;
    b = (unsigned)wv.y; uw.y = ((b | (b << 12)) & 0x000F000Fu) | 0x64006400u;
    b = (unsigned)wv.z; uw.z = ((b | (b << 12)) & 0x000F000Fu) | 0x64006400u;
    b = (unsigned)wv.w; uw.w = ((b | (b << 12)) & 0x000F000Fu) | 0x64006400u;
    const half8 c1032 = (half8)(_Float16)1032.0f; // 0x6408, exact
    return __builtin_bit_cast(half8, uw) - c1032; // exact (nib - 8)
}

// ---- pre-pass: x f32 -> f16 (512 KB -> 256 KB in d_ws), exact ----
__global__ __launch_bounds__(512) void xcvt_kernel(
    const float* __restrict__ x, _Float16* __restrict__ xf)
{
    int i = (blockIdx.x * 512 + threadIdx.x) * 4; // M*K = 131072 = 64*512*4
    float4 v = *(const float4*)(x + i);
    half4 h;
    h[0] = (_Float16)v.x; h[1] = (_Float16)v.y;
    h[2] = (_Float16)v.z; h[3] = (_Float16)v.w;
    *(half4*)(xf + i) = h;
}

// Barrier-free wave-private pipeline: no data is shared between waves, so no
// __syncthreads in the main loop. Each wave streams its own weights + x via
// global_load_lds into a private DEPTH-slot LDS ring and self-synchronizes
// with counted s_waitcnt vmcnt(N) (never 0 until drain) — 12 loads per wave
// stay in flight across the whole loop. Lane l writes LDS slot l and reads
// slot l: ds_read_b128 at lane*16 is conflict-free, zero address math.

#define WAITV(n) asm volatile("s_waitcnt vmcnt(" #n ")" ::: "memory")
#define SB() __builtin_amdgcn_sched_barrier(0)

#define ISSUE(s) {                                                  \
    gll16(gw  + (s) * 16, wbase + ((s) & 3) * WSLOT);               \
    gll16(gx0 + (s) * 32, xbase + ((s) & 3) * XSLOT);               \
    gll16(gx1 + (s) * 32, xbase + ((s) & 3) * XSLOT + 256);         \
}

#define COMPUTE(s) {                                                \
    int4 wv  = *(const int4*)&wbase[((s) & 3) * WSLOT + lane4];     \
    half8 a0 = *(const half8*)&xh[((s) & 3) * 1024 + lane8];        \
    half8 a1 = *(const half8*)&xh[((s) & 3) * 1024 + 512 + lane8];  \
    SB();                                                           \
    half8 b = unpack8(wv);                                          \
    t0 = __builtin_amdgcn_mfma_f32_16x16x32_f16(a0, b, t0, 0, 0, 0);\
    t1 = __builtin_amdgcn_mfma_f32_16x16x32_f16(a1, b, t1, 0, 0, 0);\
}

#define APPLY(sg) {                                                 \
    _Pragma("unroll")                                               \
    for (int r = 0; r < 4; ++r) {                                   \
        acc0[r] += (sg) * t0[r];                                    \
        acc1[r] += (sg) * t1[r];                                    \
    }                                                               \
    t0 = (floatx4){0.f,0.f,0.f,0.f};                                \
    t1 = (floatx4){0.f,0.f,0.f,0.f};                                \
}

__global__ __launch_bounds__(256) void int4_gemm_kernel(
    const _Float16* __restrict__ xf,  // [M][K] f16 (pre-converted)
    const int* __restrict__ wp,       // [N][K/2] int32, 2 nibbles each
    const float* __restrict__ scales, // [N][NGROUPS] f32
    float* __restrict__ out)          // [M][N] f32, pre-zeroed
{
    __shared__ int lds[4 * LWAVE];    // 48 KB staging; epilogue reduce aliases

    const int t    = threadIdx.x;
    const int lane = t & 63;
    const int w    = t >> 6;          // wave id: k-split within block
    const int n0   = blockIdx.x * BN;
    const int ks   = blockIdx.y;
    const int row  = lane & 15;       // n-row of B / m-row of A fragments
    const int quad = lane >> 4;
    const int lane4 = lane * 4;       // int index of this lane's 16B slot
    const int lane8 = lane * 8;       // half index of this lane's 16B slot

    const int kw = ks * KRANGE + w * KWAVE; // wave's contiguous 512 k

    int* wbase = &lds[w * LWAVE];
    int* xbase = wbase + DEPTH * WSLOT;
    const _Float16* xh = (const _Float16*)xbase;

    // per-lane global bases; per-step advance is a 64 B immediate offset
    const int*      gw  = wp + (long)(n0 + row) * (K / 2) + (kw >> 1) + quad * 4;
    const _Float16* gx0 = xf + (long)row * K + kw + quad * 8;
    const _Float16* gx1 = gx0 + 16 * K;

    // 4 scale groups of 128 k (one dwordx4; oldest in vmcnt FIFO, drains first)
    const float* sp = scales + (long)(n0 + row) * NGROUPS + (kw >> 7);
    const float sg0 = sp[0], sg1 = sp[1], sg2 = sp[2], sg3 = sp[3];

    floatx4 acc0 = {0,0,0,0}, acc1 = {0,0,0,0};
    floatx4 t0   = {0,0,0,0}, t1   = {0,0,0,0};

    // prologue: fill the ring (12 loads in flight)
    ISSUE(0) ISSUE(1) ISSUE(2) ISSUE(3)

    // steady state: wait step s (leave 9 in flight), compute, refill slot
    WAITV(9); COMPUTE(0)              SB(); ISSUE(4)
    WAITV(9); COMPUTE(1)              SB(); ISSUE(5)
    WAITV(9); COMPUTE(2)              SB(); ISSUE(6)
    WAITV(9); COMPUTE(3)  APPLY(sg0) SB(); ISSUE(7)
    WAITV(9); COMPUTE(4)              SB(); ISSUE(8)
    WAITV(9); COMPUTE(5)              SB(); ISSUE(9)
    WAITV(9); COMPUTE(6)              SB(); ISSUE(10)
    WAITV(9); COMPUTE(7)  APPLY(sg1) SB(); ISSUE(11)
    WAITV(9); COMPUTE(8)              SB(); ISSUE(12)
    WAITV(9); COMPUTE(9)              SB(); ISSUE(13)
    WAITV(9); COMPUTE(10)             SB(); ISSUE(14)
    WAITV(9); COMPUTE(11) APPLY(sg2) SB(); ISSUE(15)
    // drain tail
    WAITV(9); COMPUTE(12)
    WAITV(6); COMPUTE(13)
    WAITV(3); COMPUTE(14)
    WAITV(0); COMPUTE(15) APPLY(sg3)

    // ---- epilogue: reduce 4 waves' k-partials in LDS, one atomic per out ----
    __syncthreads();                  // all waves drained (vmcnt 0) & done
    float* red = (float*)lds;
    float* rw  = red + w * 32 * RS;
    #pragma unroll
    for (int r = 0; r < 4; ++r) {
        // C/D layout: col(n) = lane&15, row(m) = quad*4 + r
        rw[(quad * 4 + r) * RS + row]      = acc0[r];
        rw[(quad * 4 + r + 16) * RS + row] = acc1[r];
    }
    __syncthreads();
    #pragma unroll
    for (int i = 0; i < 2; ++i) {
        const int o = t + 256 * i;    // o = m*16 + n, 512 outputs
        const int m = o >> 4;
        const int n = o & 15;
        const int a = m * RS + n;
        const float sum = red[a] + red[32 * RS + a] + red[64 * RS + a] + red[96 * RS + a];
        atomicAdd(&out[(long)m * N + n0 + n], sum);
    }
}

extern "C" void kernel_launch(void* const* d_in, const int* in_sizes, int n_in,
                              void* d_out, int out_size, void* d_ws, size_t ws_size,
                              hipStream_t stream) {
    const float* x      = (const float*)d_in[0];
    const int* wp       = (const int*)d_in[1];
    const float* scales = (const float*)d_in[2];
    float* out          = (float*)d_out;
    _Float16* xf16      = (_Float16*)d_ws; // 256 KB

    (void)hipMemsetAsync(out, 0, (size_t)M * N * sizeof(float), stream);
    xcvt_kernel<<<dim3((M * K) / (512 * 4)), 512, 0, stream>>>(x, xf16);
    int4_gemm_kernel<<<dim3(N / BN, KSPLIT), 256, 0, stream>>>(xf16, wp, scales, out);
}

// Round 5
// 146.798 us; speedup vs baseline: 1.0945x; 1.0945x over previous
//
#include <hip/hip_runtime.h>

// Harness promotes float16 tensors to float32: x, scales, out are f32;
// weight_packed is int32, ONE BYTE (2 nibbles = 2 k-values) per element.
#define M 32
#define N 11008
#define K 4096
#define NGROUPS 32
#define BN 16                 // n-rows per block
#define KSPLIT 8              // grid-level k split
#define KRANGE (K / KSPLIT)   // 512 k per block = 2 chunks of 256
#define WPAIR 260             // ints per LDS 2-row pair: 2*128 + 4 pad
#define WTILE (8 * WPAIR)     // 2080 ints = 8.32 KB per chunk buffer
#define RS 17                 // epilogue reduce row stride (floats)

typedef _Float16 half8 __attribute__((ext_vector_type(8))); // 4 VGPRs
typedef _Float16 half4 __attribute__((ext_vector_type(4)));
typedef float floatx4 __attribute__((ext_vector_type(4)));

__device__ inline void gll16(const void* g, void* l) {
    __builtin_amdgcn_global_load_lds(
        (const __attribute__((address_space(1))) unsigned int*)g,
        (__attribute__((address_space(3))) unsigned int*)l, 16, 0, 0);
}

// 4 packed bytes -> 8 f16 of (nibble - 8), exact 0x6400 bias trick
__device__ inline half8 unpack8(int4 wv) {
    uint4 uw; unsigned int b;
    b = (unsigned)wv.x; uw.x = ((b | (b << 12)) & 0x000F000Fu) | 0x64006400u;
    b = (unsigned)wv.y; uw.y = ((b | (b << 12)) & 0x000F000Fu) | 0x64006400u;
    b = (unsigned)wv.z; uw.z = ((b | (b << 12)) & 0x000F000Fu) | 0x64006400u;
    b = (unsigned)wv.w; uw.w = ((b | (b << 12)) & 0x000F000Fu) | 0x64006400u;
    const half8 c1032 = (half8)(_Float16)1032.0f; // 0x6408, exact
    return __builtin_bit_cast(half8, uw) - c1032; // exact (nib - 8)
}

// ---- pre-pass: x f32 -> f16 (512 KB -> 256 KB in d_ws), exact ----
__global__ __launch_bounds__(512) void xcvt_kernel(
    const float* __restrict__ x, _Float16* __restrict__ xf)
{
    int i = (blockIdx.x * 512 + threadIdx.x) * 4; // M*K = 131072 = 64*512*4
    float4 v = *(const float4*)(x + i);
    half4 h;
    h[0] = (_Float16)v.x; h[1] = (_Float16)v.y;
    h[2] = (_Float16)v.z; h[3] = (_Float16)v.w;
    *(half4*)(xf + i) = h;
}

#define WAITV(n) asm volatile("s_waitcnt vmcnt(" #n ")" ::: "memory")

// TLP-first design (R0 lesson: 24+ waves/CU beat every pipelining scheme).
// Weights: both chunks' staging issued ONCE upfront via gll16 (zero VGPR),
// chunk-1 stays in flight across chunk-0 compute via counted vmcnt + raw
// s_barrier (no __syncthreads vmcnt(0) drain in the main path).
// Count-safety: gll16 builtins keep relative order; chunk-0's pair always
// has >=2 VMEM ops after it (chunk-1's pair), so WAITV(2) guarantees
// chunk-0 staged; the 4 x1 loads always follow chunk-1's pair and the
// memory-clobber WAITV(2) (no cross-motion), so WAITV(4) guarantees
// chunk-1 staged. x (no cross-lane reuse, L2-resident) -> VGPRs direct,
// compiler-tracked. LDS 16.6 KB + <=64 VGPR -> 8 blocks/CU = 32 waves/CU.
__global__ __launch_bounds__(256, 8) void int4_gemm_kernel(
    const _Float16* __restrict__ xf,  // [M][K] f16 (pre-converted)
    const int* __restrict__ wp,       // [N][K/2] int32, 2 nibbles each
    const float* __restrict__ scales, // [N][NGROUPS] f32
    float* __restrict__ out)          // [M][N] f32, pre-zeroed
{
    __shared__ int wsh[2 * WTILE];    // 16.64 KB; epilogue reduce aliases

    const int t    = threadIdx.x;
    const int lane = t & 63;
    const int w    = t >> 6;          // wave id: splits chunk k 4-ways
    const int n0   = blockIdx.x * BN;
    const int ks   = blockIdx.y;
    const int row  = lane & 15;       // n-row of B / m-row of A fragments
    const int quad = lane >> 4;
    const int kb   = ks * KRANGE;     // block k-base

    // ---- stage BOTH chunks' weights upfront (16 rows x 256k each) ----
    // pair p covers rows 2p,2p+1; wave stages pairs 2w, 2w+1; lane-contiguous
    const int p0 = w * 2, p1 = p0 + 1;
    const int h32 = lane >> 5;
    const int* ga = wp + (long)(n0 + 2 * p0 + h32) * (K / 2) + (kb >> 1) + (lane & 31) * 4;
    const int* gb = wp + (long)(n0 + 2 * p1 + h32) * (K / 2) + (kb >> 1) + (lane & 31) * 4;
    gll16(ga,       &wsh[p0 * WPAIR]);          // chunk 0
    gll16(gb,       &wsh[p1 * WPAIR]);
    gll16(ga + 128, &wsh[WTILE + p0 * WPAIR]);  // chunk 1 (+256k = +128 ints)
    gll16(gb + 128, &wsh[WTILE + p1 * WPAIR]);

    // scales: group = ks*4 + c*2 + (w>>1); one scalar per wave per chunk
    const float* sp = scales + (long)(n0 + row) * NGROUPS + ks * 4 + (w >> 1);
    const float sc0 = sp[0];
    const float sc1 = sp[2];

    // x chunk-0 fragments -> VGPRs (compiler-tracked deps)
    const _Float16* gx0 = xf + (long)row * K + kb + w * 64 + quad * 8;
    const _Float16* gx1 = gx0 + 16 * K;
    half8 a00 = *(const half8*)(gx0);
    half8 a01 = *(const half8*)(gx0 + 32);
    half8 a10 = *(const half8*)(gx1);
    half8 a11 = *(const half8*)(gx1 + 32);

    floatx4 acc0 = {0,0,0,0}, acc1 = {0,0,0,0};

    WAITV(2);                          // own chunk-0 staging landed
    __builtin_amdgcn_s_barrier();      // everyone's chunk-0 staging landed
    __builtin_amdgcn_sched_barrier(0); // no motion across the barrier

    // ---- chunk 0: wave w owns local k [w*64, w*64+64) = 2 MFMA steps ----
    {
        floatx4 t0 = {0,0,0,0}, t1 = {0,0,0,0};
        #pragma unroll
        for (int kk = 0; kk < 2; ++kk) {
            const int bidx = (row >> 1) * WPAIR + (row & 1) * 128 + w * 32 + kk * 16 + quad * 4;
            half8 b = unpack8(*(const int4*)&wsh[bidx]);
            t0 = __builtin_amdgcn_mfma_f32_16x16x32_f16(kk ? a01 : a00, b, t0, 0, 0, 0);
            t1 = __builtin_amdgcn_mfma_f32_16x16x32_f16(kk ? a11 : a10, b, t1, 0, 0, 0);
        }
        #pragma unroll
        for (int r = 0; r < 4; ++r) {
            acc0[r] += sc0 * t0[r]; // fp32 scale application, matches reference
            acc1[r] += sc0 * t1[r];
        }
    }

    // x chunk-1 fragments (reuse x0's dead registers; ~L2 latency, TLP-covered)
    half8 c00 = *(const half8*)(gx0 + 256);
    half8 c01 = *(const half8*)(gx0 + 256 + 32);
    half8 c10 = *(const half8*)(gx1 + 256);
    half8 c11 = *(const half8*)(gx1 + 256 + 32);

    WAITV(4);                          // chunk-1 staging landed (4 newest = x1)
    __builtin_amdgcn_s_barrier();
    __builtin_amdgcn_sched_barrier(0);

    // ---- chunk 1 ----
    {
        floatx4 t0 = {0,0,0,0}, t1 = {0,0,0,0};
        #pragma unroll
        for (int kk = 0; kk < 2; ++kk) {
            const int bidx = WTILE + (row >> 1) * WPAIR + (row & 1) * 128 + w * 32 + kk * 16 + quad * 4;
            half8 b = unpack8(*(const int4*)&wsh[bidx]);
            t0 = __builtin_amdgcn_mfma_f32_16x16x32_f16(kk ? c01 : c00, b, t0, 0, 0, 0);
            t1 = __builtin_amdgcn_mfma_f32_16x16x32_f16(kk ? c11 : c10, b, t1, 0, 0, 0);
        }
        #pragma unroll
        for (int r = 0; r < 4; ++r) {
            acc0[r] += sc1 * t0[r];
            acc1[r] += sc1 * t1[r];
        }
    }

    // ---- epilogue: reduce 4 waves' k-partials in LDS, one atomic per out ----
    __syncthreads();                   // full drain is free here; protects alias
    float* red = (float*)wsh;
    float* rw  = red + w * 32 * RS;
    #pragma unroll
    for (int r = 0; r < 4; ++r) {
        // C/D layout: col(n) = lane&15, row(m) = quad*4 + r
        rw[(quad * 4 + r) * RS + row]      = acc0[r];
        rw[(quad * 4 + r + 16) * RS + row] = acc1[r];
    }
    __syncthreads();
    #pragma unroll
    for (int i = 0; i < 2; ++i) {
        const int o = t + 256 * i;     // o = m*16 + n, 512 outputs
        const int m = o >> 4;
        const int n = o & 15;
        const int a = m * RS + n;
        const float sum = red[a] + red[32 * RS + a] + red[64 * RS + a] + red[96 * RS + a];
        atomicAdd(&out[(long)m * N + n0 + n], sum);
    }
}

extern "C" void kernel_launch(void* const* d_in, const int* in_sizes, int n_in,
                              void* d_out, int out_size, void* d_ws, size_t ws_size,
                              hipStream_t stream) {
    const float* x      = (const float*)d_in[0];
    const int* wp       = (const int*)d_in[1];
    const float* scales = (const float*)d_in[2];
    float* out          = (float*)d_out;
    _Float16* xf16      = (_Float16*)d_ws; // 256 KB

    (void)hipMemsetAsync(out, 0, (size_t)M * N * sizeof(float), stream);
    xcvt_kernel<<<dim3((M * K) / (512 * 4)), 512, 0, stream>>>(x, xf16);
    int4_gemm_kernel<<<dim3(N / BN, KSPLIT), 256, 0, stream>>>(xf16, wp, scales, out);
}

// Round 6
// 145.992 us; speedup vs baseline: 1.1006x; 1.0055x over previous
//
#include <hip/hip_runtime.h>

// Harness promotes float16 tensors to float32: x, scales, out are f32;
// weight_packed is int32, ONE BYTE (2 nibbles = 2 k-values) per element.
#define M 32
#define N 11008
#define K 4096
#define NGROUPS 32
#define BN 16                 // n-rows per block
#define KSPLIT 4              // grid-level k split
#define KRANGE (K / KSPLIT)   // 1024 k per block
#define BK 128                // k per chunk = exactly one scale group
#define NCHUNK (KRANGE / BK)  // 8
#define WQ 272                // ints per weight quad: 4 rows x 64 + 12 pad (stride 16 mod 32)
#define XQ 544                // halfs per x quad: 4 rows x 128 + 16 pad (1088 B)
#define WCH (4 * WQ)          // 1088 ints per chunk buffer (4.35 KB)
#define XCH (8 * XQ)          // 4352 halfs per chunk buffer (8.7 KB)

typedef _Float16 half8 __attribute__((ext_vector_type(8))); // 4 VGPRs
typedef _Float16 half4 __attribute__((ext_vector_type(4)));
typedef float floatx4 __attribute__((ext_vector_type(4)));
typedef float float8 __attribute__((ext_vector_type(8)));

__device__ inline void gll16(const void* g, void* l) {
    __builtin_amdgcn_global_load_lds(
        (const __attribute__((address_space(1))) unsigned int*)g,
        (__attribute__((address_space(3))) unsigned int*)l, 16, 0, 0);
}

// 4 packed bytes -> 8 f16 of (nibble - 8), exact 0x6400 bias trick
__device__ inline half8 unpack8(int4 wv) {
    uint4 uw; unsigned int b;
    b = (unsigned)wv.x; uw.x = ((b | (b << 12)) & 0x000F000Fu) | 0x64006400u;
    b = (unsigned)wv.y; uw.y = ((b | (b << 12)) & 0x000F000Fu) | 0x64006400u;
    b = (unsigned)wv.z; uw.z = ((b | (b << 12)) & 0x000F000Fu) | 0x64006400u;
    b = (unsigned)wv.w; uw.w = ((b | (b << 12)) & 0x000F000Fu) | 0x64006400u;
    const half8 c1032 = (half8)(_Float16)1032.0f; // 0x6408, exact
    return __builtin_bit_cast(half8, uw) - c1032; // exact (nib - 8)
}

// ---- pre-pass: x f32 -> f16 (512 KB -> 256 KB in d_ws), exact ----
__global__ __launch_bounds__(512) void xcvt_kernel(
    const float* __restrict__ x, _Float16* __restrict__ xf)
{
    int i = (blockIdx.x * 512 + threadIdx.x) * 4; // M*K = 131072 = 64*512*4
    float4 v = *(const float4*)(x + i);
    half4 h;
    h[0] = (_Float16)v.x; h[1] = (_Float16)v.y;
    h[2] = (_Float16)v.z; h[3] = (_Float16)v.w;
    *(half4*)(xf + i) = h;
}

#define WAITV(n) asm volatile("s_waitcnt vmcnt(" #n ")" ::: "memory")
#define SB() __builtin_amdgcn_sched_barrier(0)

// R0 core (all data staged via gll16, 6 blocks/CU) + T3-minimum 2-phase:
// BK=128 double-buffered (25.5 KB, occupancy unchanged), chunk c+1 staged
// BEFORE computing chunk c, counted vmcnt(3) + raw s_barrier (never a
// vmcnt(0) drain in the main loop). Count-safety: each wave issues exactly
// 3 gll16 per chunk; at iter c's WAITV(3) its outstanding FIFO is
// [stage(c) x3, stage(c+1) x3] (+ the one-time scale load, which only adds
// a harmless extra wait in iter 0), so all-but-newest-3 == chunk c landed.
// Both-sides XOR col swizzle (m173): global src col-block ^= rowInQuad,
// same XOR on ds_read -> intra-quad 4-way bank stacking becomes ~2-way (free).
__global__ __launch_bounds__(256) void int4_gemm_kernel(
    const _Float16* __restrict__ xf,  // [M][K] f16 (pre-converted)
    const int* __restrict__ wp,       // [N][K/2] int32, 2 nibbles each
    const float* __restrict__ scales, // [N][NGROUPS] f32
    float* __restrict__ out)          // [M][N] f32, pre-zeroed
{
    __shared__ int      wsh[2 * WCH]; // 8.7 KB (epilogue red aliases: 8 KB)
    __shared__ _Float16 xs [2 * XCH]; // 17.4 KB

    const int t    = threadIdx.x;
    const int lane = t & 63;
    const int w    = t >> 6;          // wave id: splits chunk k 4-ways
    const int n0   = blockIdx.x * BN;
    const int ks   = blockIdx.y;
    const int row  = lane & 15;       // n-row of B / m-row of A fragments
    const int fq   = lane >> 4;       // 16-lane group: k sub-block / staging row
    const int kb   = ks * KRANGE;

    // staging source columns, pre-swizzled: col-block (lane&15) ^ fq
    const int wcol = ((lane & 15) ^ fq) * 4; // ints within 64-int row chunk
    const int xcol = ((lane & 15) ^ fq) * 8; // halfs within 128-half row chunk

    // wave w stages: weight quad w (rows 4w+fq), x quads 2w,2w+1 (rows 8w+fq, 8w+4+fq)
    const int*      gwp = wp + (long)(n0 + w * 4 + fq) * (K / 2) + (kb >> 1) + wcol;
    const _Float16* gx0 = xf + (long)(w * 8 + fq) * K + kb + xcol;
    const _Float16* gx1 = gx0 + 4 * K;

    #define STAGE(c) {                                               \
        gll16(gwp + (c) * (BK / 2), &wsh[((c) & 1) * WCH + w * WQ]); \
        gll16(gx0 + (c) * BK, &xs[((c) & 1) * XCH + (2 * w) * XQ]);  \
        gll16(gx1 + (c) * BK, &xs[((c) & 1) * XCH + (2 * w + 1) * XQ]); \
        SB();                                                        \
    }

    // 8 chunk scales per lane's n-row (one 32B load, retired by iter-0 wait)
    const float8 sv = *(const float8*)(scales + (long)(n0 + row) * NGROUPS + ks * 8);

    // compute-side LDS offsets (same XOR as staging, riq = row&3)
    const int riq  = row & 3;
    const int bcol = ((4 * w + fq) ^ riq) * 4; // ints
    const int acol = ((4 * w + fq) ^ riq) * 8; // halfs
    const int widx = (row >> 2) * WQ + riq * 64 + bcol;
    const int xidx = (row >> 2) * XQ + riq * 128 + acol;

    floatx4 acc0 = {0,0,0,0}, acc1 = {0,0,0,0};

    STAGE(0)
    #pragma unroll
    for (int c = 0; c < NCHUNK; ++c) {
        if (c + 1 < NCHUNK) {
            STAGE(c + 1)
            WAITV(3);                 // chunk c landed; c+1 stays in flight
        } else {
            WAITV(0);                 // tail drain
        }
        __builtin_amdgcn_s_barrier(); // all waves' chunk-c staging landed
        SB();

        const int bb = (c & 1);
        int4  wv = *(const int4*)&wsh[bb * WCH + widx];
        half8 a0 = *(const half8*)&xs[bb * XCH + xidx];
        half8 a1 = *(const half8*)&xs[bb * XCH + 4 * XQ + xidx];
        half8 bf = unpack8(wv);
        const floatx4 z = {0,0,0,0};
        floatx4 t0 = __builtin_amdgcn_mfma_f32_16x16x32_f16(a0, bf, z, 0, 0, 0);
        floatx4 t1 = __builtin_amdgcn_mfma_f32_16x16x32_f16(a1, bf, z, 0, 0, 0);
        #pragma unroll
        for (int r = 0; r < 4; ++r) {
            acc0[r] += sv[c] * t0[r]; // fp32 scale application, matches reference
            acc1[r] += sv[c] * t1[r];
        }

        SB();
        __builtin_amdgcn_s_barrier(); // chunk-c buffer free for stage(c+2)
    }
    #undef STAGE

    // ---- epilogue: reduce 4 waves' k-partials in LDS, one atomic per out ----
    __syncthreads();
    float* red = (float*)wsh;         // 2048 floats = 8 KB <= wsh (8.7 KB)
    #pragma unroll
    for (int r = 0; r < 4; ++r) {
        // C/D layout: col(n) = lane&15, row(m) = fq*4 + r
        red[w * 512 + (fq * 4 + r) * 16 + row]      = acc0[r];
        red[w * 512 + (fq * 4 + r + 16) * 16 + row] = acc1[r];
    }
    __syncthreads();
    #pragma unroll
    for (int i = 0; i < 2; ++i) {
        const int o = t + 256 * i;    // o = m*16 + n
        const float sum = red[o] + red[512 + o] + red[1024 + o] + red[1536 + o];
        const int m = o >> 4;
        const int n = o & 15;
        atomicAdd(&out[(long)m * N + n0 + n], sum);
    }
}

extern "C" void kernel_launch(void* const* d_in, const int* in_sizes, int n_in,
                              void* d_out, int out_size, void* d_ws, size_t ws_size,
                              hipStream_t stream) {
    const float* x      = (const float*)d_in[0];
    const int* wp       = (const int*)d_in[1];
    const float* scales = (const float*)d_in[2];
    float* out          = (float*)d_out;
    _Float16* xf16      = (_Float16*)d_ws; // 256 KB

    (void)hipMemsetAsync(out, 0, (size_t)M * N * sizeof(float), stream);
    xcvt_kernel<<<dim3((M * K) / (512 * 4)), 512, 0, stream>>>(x, xf16);
    int4_gemm_kernel<<<dim3(N / BN, KSPLIT), 256, 0, stream>>>(xf16, wp, scales, out);
}